// Round 1
// baseline (114.428 us; speedup 1.0000x reference)
//
#include <hip/hip_runtime.h>
#include <hip/hip_bf16.h>

// Problem constants
constexpr int BN = 16384;          // batch
constexpr int DN = 64;             // nodes / input dim
constexpr int HN = 64;             // hidden
constexpr int XELEMS  = BN * DN;        // 1048576
constexpr int W1ELEMS = DN * HN * DN;   // 262144
constexpr int XCH = XELEMS / 4;         // float4 chunks of X
constexpr int WCH = W1ELEMS / 4;        // float4 chunks of W1

typedef __attribute__((ext_vector_type(8))) short short8;   // 8 x bf16 (4 VGPRs)
typedef __attribute__((ext_vector_type(4))) float f32x4;    // MFMA accumulator

__device__ __forceinline__ unsigned short f2bf(float f) {
    __hip_bfloat16 h = __float2bfloat16(f);
    return *reinterpret_cast<unsigned short*>(&h);
}

// ---------------------------------------------------------------------------
// Prep: cast X -> bf16, and W1 * adjacency -> bf16, into workspace.
// One thread per float4 chunk.  Grid covers XCH + WCH chunks exactly.
// ---------------------------------------------------------------------------
__global__ __launch_bounds__(256) void prep_kernel(
    const float* __restrict__ X, const float* __restrict__ adj,
    const float* __restrict__ W1,
    unsigned short* __restrict__ Xbf, unsigned short* __restrict__ W1bf)
{
    int t = blockIdx.x * 256 + threadIdx.x;
    if (t < XCH) {
        float4 v = reinterpret_cast<const float4*>(X)[t];
        ushort4 o;
        o.x = f2bf(v.x); o.y = f2bf(v.y); o.z = f2bf(v.z); o.w = f2bf(v.w);
        reinterpret_cast<ushort4*>(Xbf)[t] = o;
    } else {
        int c = t - XCH;
        if (c < WCH) {
            int flat = c * 4;
            int i = flat >> 12;        // / (H*D) = /4096
            int d = flat & 63;         // within-row (d is contiguous fastest dim)
            float4 w = reinterpret_cast<const float4*>(W1)[c];
            float4 a = *reinterpret_cast<const float4*>(adj + i * DN + d);
            ushort4 o;
            o.x = f2bf(w.x * a.x); o.y = f2bf(w.y * a.y);
            o.z = f2bf(w.z * a.z); o.w = f2bf(w.w * a.w);
            reinterpret_cast<ushort4*>(W1bf)[c] = o;
        }
    }
}

// ---------------------------------------------------------------------------
// Main: block = (node, 128-row batch tile). 4 waves x 32 rows each.
// Per wave: 2 M-tiles x 4 N-tiles x 2 K-steps of mfma_f32_16x16x32_bf16.
// A/B fragments loaded directly from global bf16 (L1-resident tiles, no LDS).
// Epilogue: relu * W2, butterfly-reduce over the 16-lane column groups.
// ---------------------------------------------------------------------------
__global__ __launch_bounds__(256) void mlp_kernel(
    const unsigned short* __restrict__ Xbf,    // [B][64] bf16
    const unsigned short* __restrict__ W1bf,   // [D][H][64] bf16 (adj pre-folded)
    const float* __restrict__ W2,              // [D][H] fp32
    float* __restrict__ out)                   // [B][D] fp32
{
    const int node  = blockIdx.x & 63;        // fastest-varying: write clustering
    const int btile = blockIdx.x >> 6;
    const int wave  = threadIdx.x >> 6;       // 0..3
    const int lane  = threadIdx.x & 63;
    const int row16 = lane & 15;              // A/B fragment row, C/D column
    const int quad  = lane >> 4;              // k-quad for A/B, row-quad for C/D

    const int b0 = btile * 128 + wave * 32;   // this wave's first batch row

    f32x4 acc[2][4];
#pragma unroll
    for (int mt = 0; mt < 2; ++mt)
#pragma unroll
        for (int nt = 0; nt < 4; ++nt)
            acc[mt][nt] = (f32x4){0.f, 0.f, 0.f, 0.f};

    // A frag: X[b0 + mt*16 + row16][k0 + quad*8 .. +8]
    const unsigned short* aBase = Xbf + (size_t)(b0 + row16) * DN + quad * 8;
    // B frag: W1'[node][nt*16 + row16][k0 + quad*8 .. +8]   ([N][K] storage)
    const unsigned short* bBase = W1bf + (size_t)node * (HN * DN)
                                + (size_t)row16 * DN + quad * 8;

#pragma unroll
    for (int kk = 0; kk < 2; ++kk) {
        const int k0 = kk * 32;
        short8 a0 = *reinterpret_cast<const short8*>(aBase + k0);
        short8 a1 = *reinterpret_cast<const short8*>(aBase + 16 * DN + k0);
        short8 bfrag[4];
#pragma unroll
        for (int nt = 0; nt < 4; ++nt)
            bfrag[nt] = *reinterpret_cast<const short8*>(bBase + nt * 16 * DN + k0);
#pragma unroll
        for (int nt = 0; nt < 4; ++nt) {
            acc[0][nt] = __builtin_amdgcn_mfma_f32_16x16x32_bf16(a0, bfrag[nt], acc[0][nt], 0, 0, 0);
            acc[1][nt] = __builtin_amdgcn_mfma_f32_16x16x32_bf16(a1, bfrag[nt], acc[1][nt], 0, 0, 0);
        }
    }

    // Epilogue: out[b, node] = sum_h relu(Hm[b,h]) * W2[node,h]
    // C/D layout: col(h within tile) = lane&15, row(b within tile) = quad*4 + reg.
    float w2v[4];
#pragma unroll
    for (int nt = 0; nt < 4; ++nt)
        w2v[nt] = W2[node * HN + nt * 16 + row16];

#pragma unroll
    for (int mt = 0; mt < 2; ++mt) {
        float p[4] = {0.f, 0.f, 0.f, 0.f};
#pragma unroll
        for (int nt = 0; nt < 4; ++nt) {
#pragma unroll
            for (int r = 0; r < 4; ++r)
                p[r] += fmaxf(acc[mt][nt][r], 0.f) * w2v[nt];
        }
        // reduce over the 16 columns (lanes 16q+0 .. 16q+15 share q)
#pragma unroll
        for (int off = 1; off < 16; off <<= 1) {
#pragma unroll
            for (int r = 0; r < 4; ++r)
                p[r] += __shfl_xor(p[r], off, 64);
        }
        if (row16 == 0) {
            int r0 = btile * 128 + wave * 32 + mt * 16 + quad * 4;
#pragma unroll
            for (int r = 0; r < 4; ++r)
                out[(size_t)(r0 + r) * DN + node] = p[r];
        }
    }
}

extern "C" void kernel_launch(void* const* d_in, const int* in_sizes, int n_in,
                              void* d_out, int out_size, void* d_ws, size_t ws_size,
                              hipStream_t stream) {
    const float* X   = (const float*)d_in[0];   // [B, D] fp32
    const float* adj = (const float*)d_in[1];   // [D, D] fp32
    const float* W1  = (const float*)d_in[2];   // [D, H, D] fp32
    const float* W2  = (const float*)d_in[3];   // [D, H] fp32
    float* out = (float*)d_out;                 // [B, D] fp32

    unsigned short* Xbf  = (unsigned short*)d_ws;           // 2 MB
    unsigned short* W1bf = Xbf + XELEMS;                    // 512 KB

    prep_kernel<<<(XCH + WCH + 255) / 256, 256, 0, stream>>>(X, adj, W1, Xbf, W1bf);
    mlp_kernel<<<DN * (BN / 128), 256, 0, stream>>>(Xbf, W1bf, W2, out);
}

// Round 2
// 98.640 us; speedup vs baseline: 1.1601x; 1.1601x over previous
//
#include <hip/hip_runtime.h>
#include <hip/hip_bf16.h>

// Problem constants
constexpr int BN = 16384;          // batch
constexpr int DN = 64;             // nodes / input dim
constexpr int HN = 64;             // hidden
constexpr int XELEMS  = BN * DN;        // 1048576
constexpr int W1ELEMS = DN * HN * DN;   // 262144
constexpr int XCH = XELEMS / 4;         // float4 chunks of X
constexpr int WCH = W1ELEMS / 4;        // float4 chunks of W1

typedef __attribute__((ext_vector_type(8))) short short8;   // 8 x bf16 (4 VGPRs)
typedef __attribute__((ext_vector_type(4))) float f32x4;    // MFMA accumulator

__device__ __forceinline__ unsigned short f2bf(float f) {
    __hip_bfloat16 h = __float2bfloat16(f);
    return *reinterpret_cast<unsigned short*>(&h);
}

// ---------------------------------------------------------------------------
// Prep: cast X -> bf16, and W1 * adjacency -> bf16, into workspace.
// (kept byte-identical to round 1 as a timing diagnostic)
// ---------------------------------------------------------------------------
__global__ __launch_bounds__(256) void prep_kernel(
    const float* __restrict__ X, const float* __restrict__ adj,
    const float* __restrict__ W1,
    unsigned short* __restrict__ Xbf, unsigned short* __restrict__ W1bf)
{
    int t = blockIdx.x * 256 + threadIdx.x;
    if (t < XCH) {
        float4 v = reinterpret_cast<const float4*>(X)[t];
        ushort4 o;
        o.x = f2bf(v.x); o.y = f2bf(v.y); o.z = f2bf(v.z); o.w = f2bf(v.w);
        reinterpret_cast<ushort4*>(Xbf)[t] = o;
    } else {
        int c = t - XCH;
        if (c < WCH) {
            int flat = c * 4;
            int i = flat >> 12;        // / (H*D) = /4096
            int d = flat & 63;         // within-row (d contiguous fastest dim)
            float4 w = reinterpret_cast<const float4*>(W1)[c];
            float4 a = *reinterpret_cast<const float4*>(adj + i * DN + d);
            ushort4 o;
            o.x = f2bf(w.x * a.x); o.y = f2bf(w.y * a.y);
            o.z = f2bf(w.z * a.z); o.w = f2bf(w.w * a.w);
            reinterpret_cast<ushort4*>(W1bf)[c] = o;
        }
    }
}

// ---------------------------------------------------------------------------
// Main: block = (128-row batch tile, group of 8 nodes). 4 waves x 32 rows.
// A-fragments loaded once per wave, reused across the 8-node loop.
// Per node: 8 B-loads -> 16 MFMAs -> relu*W2 -> 16-lane shuffle reduce ->
// stage into LDS. One barrier, then coalesced float4 block store (32B runs).
// ---------------------------------------------------------------------------
__global__ __launch_bounds__(256, 4) void mlp_kernel(
    const unsigned short* __restrict__ Xbf,    // [B][64] bf16
    const unsigned short* __restrict__ W1bf,   // [D][H][64] bf16 (adj folded)
    const float* __restrict__ W2,              // [D][H] fp32
    float* __restrict__ out)                   // [B][D] fp32
{
    const int ng    = blockIdx.x & 7;          // node group (8 nodes) - fastest
    const int btile = blockIdx.x >> 3;         // 128-row batch tile
    const int wave  = threadIdx.x >> 6;        // 0..3
    const int lane  = threadIdx.x & 63;
    const int row16 = lane & 15;               // A/B frag row, C/D column
    const int quad  = lane >> 4;               // A/B k-quad, C/D row-quad

    __shared__ float lds_out[128][8];          // [row][node-in-group]

    const int b0 = btile * 128 + wave * 32;

    // A frags: X[b0 + mt*16 + row16][kk*32 + quad*8 ..+8], loaded once
    const unsigned short* aBase = Xbf + (size_t)(b0 + row16) * DN + quad * 8;
    short8 afrag[2][2];
#pragma unroll
    for (int mt = 0; mt < 2; ++mt)
#pragma unroll
        for (int kk = 0; kk < 2; ++kk)
            afrag[mt][kk] = *reinterpret_cast<const short8*>(aBase + mt * 16 * DN + kk * 32);

    for (int j = 0; j < 8; ++j) {
        const int node = ng * 8 + j;
        const unsigned short* bBase = W1bf + (size_t)node * (HN * DN)
                                    + (size_t)row16 * DN + quad * 8;
        short8 bfrag[4][2];
#pragma unroll
        for (int nt = 0; nt < 4; ++nt)
#pragma unroll
            for (int kk = 0; kk < 2; ++kk)
                bfrag[nt][kk] = *reinterpret_cast<const short8*>(bBase + nt * 16 * DN + kk * 32);

        f32x4 acc[2][4];
#pragma unroll
        for (int mt = 0; mt < 2; ++mt)
#pragma unroll
            for (int nt = 0; nt < 4; ++nt)
                acc[mt][nt] = (f32x4){0.f, 0.f, 0.f, 0.f};

#pragma unroll
        for (int kk = 0; kk < 2; ++kk)
#pragma unroll
            for (int nt = 0; nt < 4; ++nt) {
                acc[0][nt] = __builtin_amdgcn_mfma_f32_16x16x32_bf16(afrag[0][kk], bfrag[nt][kk], acc[0][nt], 0, 0, 0);
                acc[1][nt] = __builtin_amdgcn_mfma_f32_16x16x32_bf16(afrag[1][kk], bfrag[nt][kk], acc[1][nt], 0, 0, 0);
            }

        // epilogue: out[b,node] = sum_h relu(H[b,h]) * W2[node,h]
        // C/D layout: h = nt*16 + (lane&15), b = mt*16 + quad*4 + reg
        float w2v[4];
#pragma unroll
        for (int nt = 0; nt < 4; ++nt)
            w2v[nt] = W2[node * HN + nt * 16 + row16];

#pragma unroll
        for (int mt = 0; mt < 2; ++mt) {
            float p[4] = {0.f, 0.f, 0.f, 0.f};
#pragma unroll
            for (int nt = 0; nt < 4; ++nt)
#pragma unroll
                for (int r = 0; r < 4; ++r)
                    p[r] += fmaxf(acc[mt][nt][r], 0.f) * w2v[nt];
#pragma unroll
            for (int off = 1; off < 16; off <<= 1)
#pragma unroll
                for (int r = 0; r < 4; ++r)
                    p[r] += __shfl_xor(p[r], off, 64);
            if (row16 == 0) {
                int rloc = wave * 32 + mt * 16 + quad * 4;
#pragma unroll
                for (int r = 0; r < 4; ++r)
                    lds_out[rloc + r][j] = p[r];
            }
        }
    }

    __syncthreads();
    // cooperative coalesced store: 128 rows x 8 floats = 256 float4
    {
        int t = threadIdx.x;
        int row = t >> 1, c = t & 1;
        float4 v = *reinterpret_cast<const float4*>(&lds_out[row][c * 4]);
        *reinterpret_cast<float4*>(out + (size_t)(btile * 128 + row) * DN + ng * 8 + c * 4) = v;
    }
}

extern "C" void kernel_launch(void* const* d_in, const int* in_sizes, int n_in,
                              void* d_out, int out_size, void* d_ws, size_t ws_size,
                              hipStream_t stream) {
    const float* X   = (const float*)d_in[0];   // [B, D] fp32
    const float* adj = (const float*)d_in[1];   // [D, D] fp32
    const float* W1  = (const float*)d_in[2];   // [D, H, D] fp32
    const float* W2  = (const float*)d_in[3];   // [D, H] fp32
    float* out = (float*)d_out;                 // [B, D] fp32

    unsigned short* Xbf  = (unsigned short*)d_ws;           // 2 MB
    unsigned short* W1bf = Xbf + XELEMS;                    // 512 KB

    prep_kernel<<<(XCH + WCH + 255) / 256, 256, 0, stream>>>(X, adj, W1, Xbf, W1bf);
    mlp_kernel<<<(BN / 128) * 8, 256, 0, stream>>>(Xbf, W1bf, W2, out);
}